// Round 13
// baseline (81.813 us; speedup 1.0000x reference)
//
#include <hip/hip_runtime.h>

// SiamFC cross-correlation: out[n,0,oh,ow] = sum_{c,i,j} x[n,c,oh+i,ow+j] * z[n,c,i,j]
// n=256, c=256, z=6x6, x=26x26, out=21x21.
//
// Round-13: NO LDS staging. Per sample, x (676 KB) + z (18 KB) are L2-resident;
// staging them through LDS was pure overhead (detour + barriers + DMA coupling).
// Each thread reads its x rows / z rows directly from global (8 x dwordx2 per
// row, row ping-pong for ILP). Zero barriers in the main loop, zero LDS bank
// traffic, waves fully independent. Thread decomposition, reduction, ws + fold
// kernel identical to R12: cc=tid&3 (channel), g bit2 (col half), t bits3-5
// (3-row tile, 7 used), h bit6 (z-row half). 6 splits {44,44,44,44,40,40}.

#define OH 21
#define OW 21
#define NTHREADS 128
#define NSPLITS 6
#define SLOT 36                // reduction slot stride (floats)
#define WS_STRIDE 448          // per-(split,n) ws slot (floats)

__global__ __launch_bounds__(NTHREADS, 3)
void siamfc_xcorr_part(const float* __restrict__ z, const float* __restrict__ x,
                       float* __restrict__ ws) {
    __shared__ float red[28 * SLOT];    // 4032 B (epilogue only)

    const int tid  = threadIdx.x;
    const int bid  = blockIdx.x;
    const int n     = bid / NSPLITS;
    const int split = bid - n * NSPLITS;
    // splits 0-3: 44 channels (11 rounds); splits 4-5: 40 channels (10 rounds)
    const int cb0    = (split < 4) ? 44 * split : 176 + 40 * (split - 4);
    const int nround = (split < 4) ? 11 : 10;

    const int cc = tid & 3;
    const int g  = (tid >> 2) & 1;      // col half: cols 10g + o
    const int t  = (tid >> 3) & 7;      // 0..7, t==7 idle
    const int h  = tid >> 6;            // z rows 3h..3h+2
    const bool active = (t < 7);

    const float2* xg2 = (const float2*)x + (size_t)n * (256 * 338);
    const float2* zg2 = (const float2*)z + (size_t)n * (256 * 18);

    float acc[33];
    #pragma unroll
    for (int v = 0; v < 33; ++v) acc[v] = 0.f;

#define LOADROW(dst, mm)                                                  \
    {                                                                     \
        const float2* rp_ = xrp + (mm) * 13;                              \
        _Pragma("unroll")                                                 \
        for (int s2 = 0; s2 < 8; ++s2) {                                  \
            float2 q_ = rp_[s2];                                          \
            dst[2 * s2] = q_.x; dst[2 * s2 + 1] = q_.y;                   \
        }                                                                 \
    }
#define FMAROW(xr, mm)                                                    \
    {                                                                     \
        _Pragma("unroll")                                                 \
        for (int zr = 0; zr < 3; ++zr) {                                  \
            const int a_ = (mm) - zr;                                     \
            if (a_ >= 0 && a_ < 3) {                                      \
                _Pragma("unroll")                                         \
                for (int j = 0; j < 6; ++j)                               \
                    _Pragma("unroll")                                     \
                    for (int o = 0; o < 11; ++o)                          \
                        acc[a_ * 11 + o] =                                \
                            fmaf(zv[zr][j], xr[o + j], acc[a_ * 11 + o]); \
            }                                                             \
        }                                                                 \
    }

    if (active) {
        #pragma unroll 1
        for (int r = 0; r < nround; ++r) {
            const int ch = cb0 + 4 * r + cc;
            // z rows 3h..3h+2: 9 float2 from global (L2-resident)
            float zv[3][6];
            {
                const float2* zp = zg2 + (size_t)ch * 18 + 9 * h;
                #pragma unroll
                for (int e = 0; e < 9; ++e) {
                    float2 q = zp[e];
                    zv[e / 3][2 * (e % 3)]     = q.x;
                    zv[e / 3][2 * (e % 3) + 1] = q.y;
                }
            }
            // x rows 3t+3h .. 3t+3h+4, floats [10g, 10g+16): row ping-pong
            const float2* xrp = xg2 + (size_t)ch * 338
                              + (size_t)(3 * t + 3 * h) * 13 + 5 * g;
            float xr0[16], xr1[16];
            LOADROW(xr0, 0)
            LOADROW(xr1, 1)
            FMAROW(xr0, 0)
            LOADROW(xr0, 2)
            FMAROW(xr1, 1)
            LOADROW(xr1, 3)
            FMAROW(xr0, 2)
            LOADROW(xr0, 4)
            FMAROW(xr1, 3)
            FMAROW(xr0, 4)
        }
    }
#undef LOADROW
#undef FMAROW

    // ---- reduce: shfl_xor across cc (lane bits 0,1), LDS slots across h
    #pragma unroll
    for (int v = 0; v < 33; ++v) {
        acc[v] += __shfl_xor(acc[v], 1, 64);
        acc[v] += __shfl_xor(acc[v], 2, 64);
    }
    if (active && cc == 0) {
        float* wsl = red + (size_t)(h * 14 + t * 2 + g) * SLOT;
        #pragma unroll
        for (int v = 0; v < 33; ++v) wsl[v] = acc[v];
    }
    __syncthreads();

    // ---- plain store of this split's 441 partials
    float* wp = ws + (size_t)(split * 256 + n) * WS_STRIDE;
    for (int o = tid; o < OH * OW; o += NTHREADS) {
        int row = o / OW, c = o - row * OW;
        int tt = row / 3, a = row - tt * 3;
        int gg = (c >= 11) ? 1 : 0;
        int vi = a * 11 + (c - 10 * gg);
        wp[o] = red[(      tt * 2 + gg) * SLOT + vi]
              + red[(14 +  tt * 2 + gg) * SLOT + vi];
    }
}

__global__ __launch_bounds__(WS_STRIDE, 4)
void siamfc_reduce(const float* __restrict__ ws, float* __restrict__ out) {
    const int n = blockIdx.x;
    const int o = threadIdx.x;
    if (o >= OH * OW) return;
    float s = 0.f;
    #pragma unroll
    for (int sp = 0; sp < NSPLITS; ++sp)
        s += ws[(size_t)(sp * 256 + n) * WS_STRIDE + o];
    out[(size_t)n * (OH * OW) + o] = s;
}

extern "C" void kernel_launch(void* const* d_in, const int* in_sizes, int n_in,
                              void* d_out, int out_size, void* d_ws, size_t ws_size,
                              hipStream_t stream) {
    const float* z = (const float*)d_in[0];
    const float* x = (const float*)d_in[1];
    float* out = (float*)d_out;
    float* wsp = (float*)d_ws;
    siamfc_xcorr_part<<<dim3(256 * NSPLITS), dim3(NTHREADS), 0, stream>>>(z, x, wsp);
    siamfc_reduce<<<dim3(256), dim3(WS_STRIDE), 0, stream>>>(wsp, out);
}

// Round 14
// 58.911 us; speedup vs baseline: 1.3888x; 1.3888x over previous
//
#include <hip/hip_runtime.h>

// SiamFC cross-correlation: out[n,0,oh,ow] = sum_{c,i,j} x[n,c,oh+i,ow+j] * z[n,c,i,j]
// n=256, c=256, z=6x6, x=26x26, out=21x21.
//
// Round-14 = Round-12 core (128 thr / 2 waves, CCON=4, global_load_lds(16B)
// double-buffered, counted vmcnt(6) + raw s_barrier, z global->registers,
// ws + fold kernel) with occupancy raised to the LDS capacity limit:
// NSPLITS=7 {40,36,36,36,36,36,36} channels -> grid 1792 = 7 blocks/CU
// (LDS 21.6 KB -> alloc ~22.5 KB, 7 x 22.5 = 157.7 KB <= 160 KB).
// +17% independent DMA streams/CU; max rounds per block 11 -> 10.

#define OH 21
#define OW 21
#define XBUF 2704              // 4 ch * 676 floats
#define BUFSTRIDE 2704
#define NTHREADS 128
#define NSPLITS 7
#define SLOT 36                // reduction slot stride (floats)
#define WS_STRIDE 448          // per-(split,n) ws slot (floats)

typedef __attribute__((address_space(3))) unsigned int lds_u32_t;
typedef __attribute__((address_space(1))) const unsigned int glb_u32_t;

__device__ __forceinline__ void gload16(const void* g, void* l) {
    __builtin_amdgcn_global_load_lds((glb_u32_t*)g, (lds_u32_t*)l, 16, 0, 0);
}

__global__ __launch_bounds__(NTHREADS, 3)
void siamfc_xcorr_part(const float* __restrict__ z, const float* __restrict__ x,
                       float* __restrict__ ws) {
    __shared__ __align__(16) float lds[2 * BUFSTRIDE];   // 21632 B

    const int tid  = threadIdx.x;
    const int lane = tid & 63;
    const int w    = tid >> 6;          // wave id == h
    const int bid  = blockIdx.x;
    const int n     = bid / NSPLITS;
    const int split = bid - n * NSPLITS;
    // split 0: 40 channels (10 rounds); splits 1-6: 36 channels (9 rounds)
    const int cb0    = (split == 0) ? 0 : 40 + 36 * (split - 1);
    const int nround = (split == 0) ? 10 : 9;

    const int cc = tid & 3;
    const int g  = (tid >> 2) & 1;      // col half: cols 10g + o
    const int t  = (tid >> 3) & 7;      // 0..7, t==7 idle in compute
    const int h  = w;
    const bool active = (t < 7);

    const float4* xg4 = (const float4*)x + (size_t)n * (256 * 169);
    const float2* zg2 = (const float2*)z + (size_t)n * (256 * 18);

    // 6 per-wave global_load_lds for round r into buffer b (x only)
    auto issue = [&](int r, int b) {
        const float4* xsrc = xg4 + (size_t)(cb0 + 4 * r) * 169;  // 676 quads
        float* xb = lds + b * BUFSTRIDE;
        #pragma unroll
        for (int k = 0; k < 5; ++k)                      // quads k*128 + tid
            gload16(xsrc + k * 128 + tid, xb + (size_t)(k * 128 + w * 64) * 4);
        if (lane < 18)                                   // x quads 640..675
            gload16(xsrc + 640 + w * 18 + lane, xb + (size_t)(640 + w * 18) * 4);
    };

    float acc[33];
    #pragma unroll
    for (int v = 0; v < 33; ++v) acc[v] = 0.f;

    issue(0, 0);

    #pragma unroll 1
    for (int r = 0; r < nround; ++r) {
        // ---- z for round r: global -> registers (issued BEFORE next x-DMA,
        //      so vmcnt(6) forces them complete too). All lanes load.
        float2 zq[9];
        {
            const float2* zp = zg2 + (size_t)(cb0 + 4 * r + cc) * 18 + 9 * h;
            #pragma unroll
            for (int e = 0; e < 9; ++e) zq[e] = zp[e];
        }
        if (r + 1 < nround) {
            issue(r + 1, (r + 1) & 1);
            asm volatile("s_waitcnt vmcnt(6)" ::: "memory");  // round-r x DMA + z done
        } else {
            asm volatile("s_waitcnt vmcnt(0)" ::: "memory");
        }
        __builtin_amdgcn_s_barrier();
        asm volatile("" ::: "memory");

        if (active) {
            const float* xb = lds + (r & 1) * BUFSTRIDE;
            float zv[3][6];
            #pragma unroll
            for (int e = 0; e < 9; ++e) {
                zv[e / 3][2 * (e % 3)]     = zq[e].x;
                zv[e / 3][2 * (e % 3) + 1] = zq[e].y;
            }
            const float* xcb = xb + cc * 676;
            #pragma unroll
            for (int m = 0; m < 5; ++m) {                // x rows 3t+3h+m
                const int row = 3 * t + 3 * h + m;       // <= 25
                const float2* rp = (const float2*)xcb + 13 * row + 5 * g;
                float xr[16];                            // row floats 10g..10g+15
                #pragma unroll
                for (int s = 0; s < 8; ++s) {
                    float2 q = rp[s];
                    xr[2 * s] = q.x; xr[2 * s + 1] = q.y;
                }
                #pragma unroll
                for (int zr = 0; zr < 3; ++zr) {
                    const int a = m - zr;                // output row 3t+a
                    if (a >= 0 && a < 3) {
                        #pragma unroll
                        for (int j = 0; j < 6; ++j)
                            #pragma unroll
                            for (int o = 0; o < 11; ++o) // out col 10g+o
                                acc[a * 11 + o] = fmaf(zv[zr][j], xr[o + j], acc[a * 11 + o]);
                    }
                }
            }
        }
        __builtin_amdgcn_s_barrier();
        asm volatile("" ::: "memory");
    }

    // ---- reduce: shfl_xor across cc (lane bits 0,1), LDS slots across h
    #pragma unroll
    for (int v = 0; v < 33; ++v) {
        acc[v] += __shfl_xor(acc[v], 1, 64);
        acc[v] += __shfl_xor(acc[v], 2, 64);
    }
    if (active && cc == 0) {
        float* wsl = lds + (size_t)(h * 14 + t * 2 + g) * SLOT;
        #pragma unroll
        for (int v = 0; v < 33; ++v) wsl[v] = acc[v];
    }
    __syncthreads();

    // ---- plain store of this split's 441 partials (no atomics, no memset)
    float* wp = ws + (size_t)(split * 256 + n) * WS_STRIDE;
    for (int o = tid; o < OH * OW; o += NTHREADS) {
        int row = o / OW, c = o - row * OW;
        int tt = row / 3, a = row - tt * 3;
        int gg = (c >= 11) ? 1 : 0;
        int vi = a * 11 + (c - 10 * gg);
        wp[o] = lds[(      tt * 2 + gg) * SLOT + vi]
              + lds[(14 +  tt * 2 + gg) * SLOT + vi];
    }
}

__global__ __launch_bounds__(WS_STRIDE, 4)
void siamfc_reduce(const float* __restrict__ ws, float* __restrict__ out) {
    const int n = blockIdx.x;
    const int o = threadIdx.x;
    if (o >= OH * OW) return;
    float s = 0.f;
    #pragma unroll
    for (int sp = 0; sp < NSPLITS; ++sp)
        s += ws[(size_t)(sp * 256 + n) * WS_STRIDE + o];
    out[(size_t)n * (OH * OW) + o] = s;
}

extern "C" void kernel_launch(void* const* d_in, const int* in_sizes, int n_in,
                              void* d_out, int out_size, void* d_ws, size_t ws_size,
                              hipStream_t stream) {
    const float* z = (const float*)d_in[0];
    const float* x = (const float*)d_in[1];
    float* out = (float*)d_out;
    float* wsp = (float*)d_ws;
    siamfc_xcorr_part<<<dim3(256 * NSPLITS), dim3(NTHREADS), 0, stream>>>(z, x, wsp);
    siamfc_reduce<<<dim3(256), dim3(WS_STRIDE), 0, stream>>>(wsp, out);
}